// Round 1
// baseline (189.592 us; speedup 1.0000x reference)
//
#include <hip/hip_runtime.h>

typedef unsigned short u16;
typedef __attribute__((ext_vector_type(8))) short short8;
typedef __attribute__((ext_vector_type(4))) short short4v;
typedef __attribute__((ext_vector_type(4))) float f32x4;

#define DEV static __device__ __forceinline__

static_assert(sizeof(short8) == 16, "short8 must be 16B");

// ---------- helpers ----------
DEV u16 f2b(float f) {                       // fp32 -> bf16, round-to-nearest-even
  union { float f; unsigned u; } a; a.f = f;
  unsigned u = a.u;
  unsigned r = (u + 0x7FFFu + ((u >> 16) & 1u)) >> 16;
  return (u16)r;
}
DEV float b2f(u16 h) {
  union { unsigned u; float f; } a; a.u = ((unsigned)h) << 16;
  return a.f;
}

// MFMA via inline asm: avoids builtin operand-type ambiguity (V8y vs V8s) on gfx950.
// A-frag: lane holds A[row=l&15][k=8*(l>>4)+j]; B-frag: B[k=8*(l>>4)+j][col=l&15];
// D: D[row=4*(l>>4)+r][col=l&15]  (learn_hip m89/m91 verified)
DEV f32x4 mfma16(short8 a, short8 b, f32x4 c) {
  asm volatile("v_mfma_f32_16x16x32_bf16 %0, %1, %2, %0" : "+v"(c) : "v"(a), "v"(b));
  return c;
}
// Hazard fences: hazard recognizer can't see MFMA inside inline asm, so we insert
// the MFMA-write -> VALU-read wait states ourselves (16 cycles covers 4-pass 16x16).
DEV f32x4 fence_nops(f32x4 c) { asm volatile("s_nop 7\n\ts_nop 7" : "+v"(c)); return c; }
DEV f32x4 fence0(f32x4 c)     { asm volatile("" : "+v"(c)); return c; }

// ---------- problem dims ----------
constexpr int Bz = 8, Nseq = 1024, Emb = 768, Hh = 8, Dh = 96;
constexpr int Mrows = Bz * Nseq;    // 8192
constexpr int K3 = 3 * Emb;         // 2304

// ---------- kernel 1: x fp32 -> bf16 ----------
__global__ __launch_bounds__(256) void k_cvt_x(const float* __restrict__ src,
                                               u16* __restrict__ dst) {
  int i = (blockIdx.x * 256 + threadIdx.x) * 4;
  float4 v = *(const float4*)(src + i);
  short4v o;
  o[0] = (short)f2b(v.x); o[1] = (short)f2b(v.y);
  o[2] = (short)f2b(v.z); o[3] = (short)f2b(v.w);
  *(short4v*)(dst + i) = o;
}

// ---------- kernel 2: transpose + cvt: src fp32 [R][C] -> dst bf16 [C][R] ----------
__global__ __launch_bounds__(256) void k_tcvt(const float* __restrict__ src,
                                              u16* __restrict__ dst, int R, int C) {
  __shared__ float t[32][33];
  int bx = blockIdx.x * 32;   // col tile in src
  int by = blockIdx.y * 32;   // row tile in src
  int c = threadIdx.x & 31, r8 = threadIdx.x >> 5;   // r8: 0..7
#pragma unroll
  for (int p = 0; p < 4; ++p) {
    int r = r8 + p * 8;
    t[r][c] = src[(size_t)(by + r) * C + bx + c];
  }
  __syncthreads();
#pragma unroll
  for (int p = 0; p < 4; ++p) {
    int r = r8 + p * 8;   // row in dst = col in src
    dst[(size_t)(bx + r) * R + by + c] = f2b(t[c][r]);
  }
}

// ---------- kernel 3: GEMM  C[M][Nn] = A[M][K] * Bt[Nn][K]^T + bias ----------
// 128x128 tile, 4 waves (2x2), each wave 64x64 = 4x4 frags of 16x16x32.
template <int F32OUT>
__global__ __launch_bounds__(256, 2) void k_gemm_bt(
    const u16* __restrict__ A, const u16* __restrict__ Bt,
    const float* __restrict__ bias,
    u16* __restrict__ obf, float* __restrict__ of32,
    int Nn, int Kdim) {
  __shared__ u16 Al[128][40];   // +8 pad: 2-way max on ds_read_b128
  __shared__ u16 Bl[128][40];
  int m0 = blockIdx.x * 128, n0 = blockIdx.y * 128;
  int tid = threadIdx.x;
  int w = tid >> 6, l = tid & 63, lr = l >> 4, lc = l & 15;
  int wr = w >> 1, wc = w & 1;
  f32x4 acc[4][4] = {};
  int nkt = Kdim >> 5;
  for (int kt = 0; kt < nkt; ++kt) {
    __syncthreads();   // previous compute done before LDS overwrite
#pragma unroll
    for (int i = 0; i < 2; ++i) {
      int idx = tid + i * 256;            // 512 chunks of 16B
      int r = idx >> 2, c8 = (idx & 3) * 8;
      *(short8*)&Al[r][c8] = *(const short8*)(A + (size_t)(m0 + r) * Kdim + kt * 32 + c8);
      *(short8*)&Bl[r][c8] = *(const short8*)(Bt + (size_t)(n0 + r) * Kdim + kt * 32 + c8);
    }
    __syncthreads();
    short8 af[4];
#pragma unroll
    for (int mi = 0; mi < 4; ++mi)
      af[mi] = *(const short8*)&Al[wr * 64 + mi * 16 + lc][lr * 8];
#pragma unroll
    for (int ni = 0; ni < 4; ++ni) {
      short8 bf = *(const short8*)&Bl[wc * 64 + ni * 16 + lc][lr * 8];
#pragma unroll
      for (int mi = 0; mi < 4; ++mi)
        acc[mi][ni] = mfma16(af[mi], bf, acc[mi][ni]);
    }
  }
  // MFMA->VALU hazard fence (one real fence, rest order through asm)
  acc[3][3] = fence_nops(acc[3][3]);
#pragma unroll
  for (int mi = 0; mi < 4; ++mi)
#pragma unroll
    for (int ni = 0; ni < 4; ++ni)
      if (!(mi == 3 && ni == 3)) acc[mi][ni] = fence0(acc[mi][ni]);

#pragma unroll
  for (int mi = 0; mi < 4; ++mi) {
#pragma unroll
    for (int ni = 0; ni < 4; ++ni) {
      int col = n0 + wc * 64 + ni * 16 + lc;
      float bv = bias[col];
      int row0 = m0 + wr * 64 + mi * 16 + lr * 4;
#pragma unroll
      for (int r = 0; r < 4; ++r) {
        float v = acc[mi][ni][r] + bv;
        if (F32OUT) of32[(size_t)(row0 + r) * Nn + col] = v;
        else        obf[(size_t)(row0 + r) * Nn + col] = f2b(v);
      }
    }
  }
}

// ---------- kernel 4: qkv[8192][2304] -> q[B,H,N,D]*scale, k[B,H,N,D], vT[B,H,D,N] ----------
__global__ __launch_bounds__(256) void k_reshape(const u16* __restrict__ qkv,
                                                 u16* __restrict__ q,
                                                 u16* __restrict__ kk,
                                                 u16* __restrict__ vt) {
  __shared__ u16 vtile[96][136];   // swizzled columns, 16B-aligned rows
  int blk = blockIdx.x;            // b*64 + h*8 + nt
  int b = blk >> 6, h = (blk >> 3) & 7, nt = blk & 7;
  int n0 = nt * 128;
  const float scale = 0.03608439182435161f;  // 768^-0.5
  int tid = threadIdx.x;
#pragma unroll
  for (int i = 0; i < 6; ++i) {
    int task = tid + i * 256;          // 128 rows x 12 groups of 8 d
    int r = task / 12, g = task % 12;
    const u16* src = qkv + (size_t)(b * 1024 + n0 + r) * 2304 + h * 288 + g * 24;
    short8 c0 = *(const short8*)(src);
    short8 c1 = *(const short8*)(src + 8);
    short8 c2 = *(const short8*)(src + 16);
    // cols 24g+3j+s : s=0 -> q, 1 -> k, 2 -> v  (d = 8g+j)
    short8 qs, ks;
    qs[0] = c0[0]; qs[1] = c0[3]; qs[2] = c0[6]; qs[3] = c1[1];
    qs[4] = c1[4]; qs[5] = c1[7]; qs[6] = c2[2]; qs[7] = c2[5];
    ks[0] = c0[1]; ks[1] = c0[4]; ks[2] = c0[7]; ks[3] = c1[2];
    ks[4] = c1[5]; ks[5] = c2[0]; ks[6] = c2[3]; ks[7] = c2[6];
    short vvv[8];
    vvv[0] = c0[2]; vvv[1] = c0[5]; vvv[2] = c1[0]; vvv[3] = c1[3];
    vvv[4] = c1[6]; vvv[5] = c2[1]; vvv[6] = c2[4]; vvv[7] = c2[7];
#pragma unroll
    for (int j = 0; j < 8; ++j)
      qs[j] = (short)f2b(b2f((u16)qs[j]) * scale);    // fold softmax scale into q
    size_t base = ((size_t)((b * 8 + h) * 1024) + n0 + r) * 96 + g * 8;
    *(short8*)(q + base) = qs;
    *(short8*)(kk + base) = ks;
    int swz = (g & 7) << 4;
#pragma unroll
    for (int j = 0; j < 8; ++j)
      vtile[g * 8 + j][r ^ swz] = (u16)vvv[j];
  }
  __syncthreads();
#pragma unroll
  for (int i = 0; i < 6; ++i) {
    int task = tid + i * 256;          // 96 d x 16 chunks
    int d = task >> 4, c = task & 15;
    int swz = ((d >> 3) & 7) << 4;
    short8 v = *(const short8*)&vtile[d][(c * 8) ^ swz];
    *(short8*)(vt + ((size_t)((b * 8 + h) * 96) + d) * 1024 + n0 + c * 8) = v;
  }
}

// ---------- kernel 5: flash attention ----------
// block = (b,h,qt): 128 q rows, 4 waves x 32 rows. K tiles of 128 staged in LDS.
__global__ __launch_bounds__(256, 2) void k_attn(const u16* __restrict__ q,
                                                 const u16* __restrict__ kk,
                                                 const u16* __restrict__ vt,
                                                 u16* __restrict__ ctx) {
  __shared__ u16 K_lds[128][104];       // +8 pad
  __shared__ u16 P_lds[4][32][136];     // per-wave, +8 pad
  int blk = blockIdx.x;                 // bh*8 + qt
  int bh = blk >> 3, qt = blk & 7;
  int b = bh >> 3, h = bh & 7;
  int tid = threadIdx.x, w = tid >> 6, l = tid & 63;
  int lr = l >> 4, lc = l & 15;
  int q0 = qt * 128 + w * 32;           // wave's first q row in this (b,h)
  const u16* qptr = q + (size_t)bh * 1024 * 96;
  const u16* kptr = kk + (size_t)bh * 1024 * 96;
  const u16* vptr = vt + (size_t)bh * 96 * 1024;

  short8 qf[2][3];
#pragma unroll
  for (int mf = 0; mf < 2; ++mf)
#pragma unroll
    for (int kf = 0; kf < 3; ++kf)
      qf[mf][kf] = *(const short8*)(qptr + (size_t)(q0 + mf * 16 + lc) * 96 + kf * 32 + lr * 8);

  float mrow[2][4], lrow[2][4];
#pragma unroll
  for (int mf = 0; mf < 2; ++mf)
#pragma unroll
    for (int r = 0; r < 4; ++r) { mrow[mf][r] = -INFINITY; lrow[mf][r] = 0.f; }
  f32x4 oacc[2][6] = {};

  for (int kt = 0; kt < 8; ++kt) {
    __syncthreads();   // everyone done reading previous K tile
#pragma unroll
    for (int i = 0; i < 6; ++i) {
      int task = tid + i * 256;        // 128 rows x 12 chunks
      int rr = task / 12, c8 = task % 12;
      *(short8*)&K_lds[rr][c8 * 8] =
          *(const short8*)(kptr + (size_t)(kt * 128 + rr) * 96 + c8 * 8);
    }
    __syncthreads();

    // S = Q K^T   (q pre-scaled)
    f32x4 sacc[2][8] = {};
#pragma unroll
    for (int nf = 0; nf < 8; ++nf) {
#pragma unroll
      for (int kf = 0; kf < 3; ++kf) {
        short8 kb = *(const short8*)&K_lds[nf * 16 + lc][kf * 32 + lr * 8];
        sacc[0][nf] = mfma16(qf[0][kf], kb, sacc[0][nf]);
        sacc[1][nf] = mfma16(qf[1][kf], kb, sacc[1][nf]);
      }
    }
    sacc[1][7] = fence_nops(sacc[1][7]);
#pragma unroll
    for (int mf = 0; mf < 2; ++mf)
#pragma unroll
      for (int nf = 0; nf < 8; ++nf)
        if (!(mf == 1 && nf == 7)) sacc[mf][nf] = fence0(sacc[mf][nf]);

    // online softmax; rows: 4*lr + r (+16*mf); cols: nf*16 + lc
#pragma unroll
    for (int mf = 0; mf < 2; ++mf) {
#pragma unroll
      for (int r = 0; r < 4; ++r) {
        float mx = sacc[mf][0][r];
#pragma unroll
        for (int nf = 1; nf < 8; ++nf) mx = fmaxf(mx, sacc[mf][nf][r]);
#pragma unroll
        for (int d = 1; d < 16; d <<= 1) mx = fmaxf(mx, __shfl_xor(mx, d));
        float nm = fmaxf(mrow[mf][r], mx);
        float sc = __expf(mrow[mf][r] - nm);   // 0 on first tile
        mrow[mf][r] = nm;
        float rs = 0.f;
#pragma unroll
        for (int nf = 0; nf < 8; ++nf) {
          float p = __expf(sacc[mf][nf][r] - nm);
          sacc[mf][nf][r] = p;
          rs += p;
        }
#pragma unroll
        for (int d = 1; d < 16; d <<= 1) rs += __shfl_xor(rs, d);
        lrow[mf][r] = lrow[mf][r] * sc + rs;
#pragma unroll
        for (int nf = 0; nf < 6; ++nf) oacc[mf][nf][r] *= sc;
      }
    }

    // P -> LDS (relayout for PV A-operand)
#pragma unroll
    for (int mf = 0; mf < 2; ++mf)
#pragma unroll
      for (int nf = 0; nf < 8; ++nf)
#pragma unroll
        for (int r = 0; r < 4; ++r)
          P_lds[w][mf * 16 + lr * 4 + r][nf * 16 + lc] = f2b(sacc[mf][nf][r]);

    // O += P V
#pragma unroll
    for (int kf = 0; kf < 4; ++kf) {
      short8 pa0 = *(const short8*)&P_lds[w][lc][kf * 32 + lr * 8];
      short8 pa1 = *(const short8*)&P_lds[w][16 + lc][kf * 32 + lr * 8];
#pragma unroll
      for (int nf = 0; nf < 6; ++nf) {
        short8 vb = *(const short8*)(vptr + (size_t)(nf * 16 + lc) * 1024 +
                                     kt * 128 + kf * 32 + lr * 8);
        oacc[0][nf] = mfma16(pa0, vb, oacc[0][nf]);
        oacc[1][nf] = mfma16(pa1, vb, oacc[1][nf]);
      }
    }
  }

  oacc[1][5] = fence_nops(oacc[1][5]);
#pragma unroll
  for (int mf = 0; mf < 2; ++mf)
#pragma unroll
    for (int nf = 0; nf < 6; ++nf)
      if (!(mf == 1 && nf == 5)) oacc[mf][nf] = fence0(oacc[mf][nf]);

#pragma unroll
  for (int mf = 0; mf < 2; ++mf) {
    float inv[4];
#pragma unroll
    for (int r = 0; r < 4; ++r) inv[r] = 1.0f / lrow[mf][r];
#pragma unroll
    for (int nf = 0; nf < 6; ++nf) {
#pragma unroll
      for (int r = 0; r < 4; ++r) {
        int row = b * 1024 + qt * 128 + w * 32 + mf * 16 + lr * 4 + r;
        ctx[(size_t)row * 768 + h * 96 + nf * 16 + lc] = f2b(oacc[mf][nf][r] * inv[r]);
      }
    }
  }
}

// ---------- launch ----------
extern "C" void kernel_launch(void* const* d_in, const int* in_sizes, int n_in,
                              void* d_out, int out_size, void* d_ws, size_t ws_size,
                              hipStream_t stream) {
  const float* x     = (const float*)d_in[0];
  const float* Wqkv  = (const float*)d_in[1];
  const float* bqkv  = (const float*)d_in[2];
  const float* Wproj = (const float*)d_in[3];
  const float* bproj = (const float*)d_in[4];
  float* out = (float*)d_out;

  char* ws = (char*)d_ws;
  u16* xb     = (u16*)(ws);                      // 12,582,912 B (reused as ctx)
  u16* wqkvT  = (u16*)(ws + 12582912);           //  3,538,944 B
  u16* wprojT = (u16*)(ws + 16121856);           //  1,179,648 B
  u16* qkvb   = (u16*)(ws + 17301504);           // 37,748,736 B
  u16* qb     = (u16*)(ws + 55050240);           // 12,582,912 B
  u16* kb     = (u16*)(ws + 67633152);           // 12,582,912 B
  u16* vtb    = (u16*)(ws + 80216064);           // 12,582,912 B  (total ~92.8 MB)
  u16* ctx    = xb;                              // xb dead after QKV GEMM

  k_cvt_x<<<6144, 256, 0, stream>>>(x, xb);
  k_tcvt<<<dim3(K3 / 32, Emb / 32), 256, 0, stream>>>(Wqkv, wqkvT, Emb, K3);
  k_tcvt<<<dim3(Emb / 32, Emb / 32), 256, 0, stream>>>(Wproj, wprojT, Emb, Emb);
  k_gemm_bt<0><<<dim3(Mrows / 128, K3 / 128), 256, 0, stream>>>(
      xb, wqkvT, bqkv, qkvb, nullptr, K3, Emb);
  k_reshape<<<512, 256, 0, stream>>>(qkvb, qb, kb, vtb);
  k_attn<<<512, 256, 0, stream>>>(qb, kb, vtb, ctx);
  k_gemm_bt<1><<<dim3(Mrows / 128, Emb / 128), 256, 0, stream>>>(
      ctx, wprojT, bproj, nullptr, out, Emb, Emb);
}

// Round 2
// 159.178 us; speedup vs baseline: 1.1911x; 1.1911x over previous
//
#include <hip/hip_runtime.h>

typedef unsigned short u16;
typedef __attribute__((ext_vector_type(8))) short short8;
typedef __attribute__((ext_vector_type(4))) short short4v;
typedef __attribute__((ext_vector_type(4))) float f32x4;

#define DEV static __device__ __forceinline__

static_assert(sizeof(short8) == 16, "short8 must be 16B");

// ---------- helpers ----------
DEV u16 f2b(float f) {                       // fp32 -> bf16, round-to-nearest-even
  union { float f; unsigned u; } a; a.f = f;
  unsigned u = a.u;
  unsigned r = (u + 0x7FFFu + ((u >> 16) & 1u)) >> 16;
  return (u16)r;
}
DEV float b2f(u16 h) {
  union { unsigned u; float f; } a; a.u = ((unsigned)h) << 16;
  return a.f;
}

DEV f32x4 mfma16(short8 a, short8 b, f32x4 c) {
  asm volatile("v_mfma_f32_16x16x32_bf16 %0, %1, %2, %0" : "+v"(c) : "v"(a), "v"(b));
  return c;
}
DEV f32x4 fence_nops(f32x4 c) { asm volatile("s_nop 7\n\ts_nop 7" : "+v"(c)); return c; }
DEV f32x4 fence0(f32x4 c)     { asm volatile("" : "+v"(c)); return c; }

// async global->LDS, 16B per lane; LDS dest must be wave-uniform base + lane*16
DEV void gl_lds16(const u16* g, u16* l) {
  __builtin_amdgcn_global_load_lds(
      (const __attribute__((address_space(1))) void*)g,
      (__attribute__((address_space(3))) void*)l, 16, 0, 0);
}

// barrier that does NOT drain vmcnt (keeps register prefetch loads in flight)
#define BAR() asm volatile("s_waitcnt lgkmcnt(0)\n\ts_barrier" ::: "memory")

// ---------- problem dims ----------
constexpr int Bz = 8, Nseq = 1024, Emb = 768, Hh = 8, Dh = 96;
constexpr int Mrows = Bz * Nseq;    // 8192
constexpr int K3 = 3 * Emb;         // 2304
constexpr float QSCALE = 0.03608439182435161f;  // 768^-0.5

// ---------- kernel 1: x fp32 -> bf16 ----------
__global__ __launch_bounds__(256) void k_cvt_x(const float* __restrict__ src,
                                               u16* __restrict__ dst) {
  int i = (blockIdx.x * 256 + threadIdx.x) * 4;
  float4 v = *(const float4*)(src + i);
  short4v o;
  o[0] = (short)f2b(v.x); o[1] = (short)f2b(v.y);
  o[2] = (short)f2b(v.z); o[3] = (short)f2b(v.w);
  *(short4v*)(dst + i) = o;
}

// ---------- kernel 2: transpose + cvt (+optional qkv column permutation) ----------
// src fp32 [R][C] -> dst bf16 [C'][R], C' = perm(C). PERM: col (h*288+d*3+s) ->
// row s*768+h*96+d, q-section (s==0) scaled by QSCALE.
template <int PERM>
__global__ __launch_bounds__(256) void k_tcvt(const float* __restrict__ src,
                                              u16* __restrict__ dst, int R, int C) {
  __shared__ float t[32][33];
  int bx = blockIdx.x * 32;   // col tile in src
  int by = blockIdx.y * 32;   // row tile in src
  int c = threadIdx.x & 31, r8 = threadIdx.x >> 5;   // r8: 0..7
#pragma unroll
  for (int p = 0; p < 4; ++p) {
    int r = r8 + p * 8;
    t[r][c] = src[(size_t)(by + r) * C + bx + c];
  }
  __syncthreads();
#pragma unroll
  for (int p = 0; p < 4; ++p) {
    int r = r8 + p * 8;
    int co = bx + r;           // dst row before permutation = src col
    int row = co;
    float mul = 1.f;
    if (PERM) {
      int h = co / 288, rem = co - h * 288;
      int d = rem / 3, s = rem - d * 3;
      row = s * 768 + h * 96 + d;
      if (s == 0) mul = QSCALE;
    }
    dst[(size_t)row * R + by + c] = f2b(t[c][r] * mul);
  }
}

// ---------- kernel 2b: permuted (and q-scaled) qkv bias, fp32 ----------
__global__ __launch_bounds__(256) void k_permbias(const float* __restrict__ b,
                                                  float* __restrict__ bp) {
  int co = blockIdx.x * 256 + threadIdx.x;
  if (co < 2304) {
    int h = co / 288, rem = co - h * 288, d = rem / 3, s = rem - d * 3;
    bp[s * 768 + h * 96 + d] = b[co] * (s == 0 ? QSCALE : 1.f);
  }
}

// ---------- kernel 3: GEMM  C[M][Nn] = A[M][K] * Bt[Nn][K]^T + bias ----------
// m97 structure: 128x128 tile, BK=32, linear LDS + global_load_lds dwordx4.
template <int F32OUT>
__global__ __launch_bounds__(256, 2) void k_gemm_bt(
    const u16* __restrict__ A, const u16* __restrict__ Bt,
    const float* __restrict__ bias,
    u16* __restrict__ obf, float* __restrict__ of32,
    int Nn, int Kdim) {
  __shared__ __align__(16) u16 Al[128 * 32];
  __shared__ __align__(16) u16 Bl[128 * 32];
  int m0 = blockIdx.x * 128, n0 = blockIdx.y * 128;
  int tid = threadIdx.x;
  int w = tid >> 6, l = tid & 63, lr = l >> 4, lc = l & 15;
  int wr = w >> 1, wc = w & 1;
  f32x4 acc[4][4] = {};
  int nkt = Kdim >> 5;
  for (int kt = 0; kt < nkt; ++kt) {
    __syncthreads();   // previous compute done before LDS overwrite
#pragma unroll
    for (int i = 0; i < 2; ++i) {
      int idx = i * 256 + tid;              // 512 chunks of 16B per matrix
      int r = idx >> 2, c8 = (idx & 3) * 8;
      gl_lds16(A + (size_t)(m0 + r) * Kdim + kt * 32 + c8, &Al[idx * 8]);
      gl_lds16(Bt + (size_t)(n0 + r) * Kdim + kt * 32 + c8, &Bl[idx * 8]);
    }
    __syncthreads();   // compiler drains vmcnt before barrier -> staging visible
    short8 af[4];
#pragma unroll
    for (int mi = 0; mi < 4; ++mi)
      af[mi] = *(const short8*)&Al[(wr * 64 + mi * 16 + lc) * 32 + lr * 8];
#pragma unroll
    for (int ni = 0; ni < 4; ++ni) {
      short8 bf = *(const short8*)&Bl[(wc * 64 + ni * 16 + lc) * 32 + lr * 8];
#pragma unroll
      for (int mi = 0; mi < 4; ++mi)
        acc[mi][ni] = mfma16(af[mi], bf, acc[mi][ni]);
    }
  }
  acc[3][3] = fence_nops(acc[3][3]);
#pragma unroll
  for (int mi = 0; mi < 4; ++mi)
#pragma unroll
    for (int ni = 0; ni < 4; ++ni)
      if (!(mi == 3 && ni == 3)) acc[mi][ni] = fence0(acc[mi][ni]);

#pragma unroll
  for (int mi = 0; mi < 4; ++mi) {
#pragma unroll
    for (int ni = 0; ni < 4; ++ni) {
      int col = n0 + wc * 64 + ni * 16 + lc;
      float bv = bias[col];
      int row0 = m0 + wr * 64 + mi * 16 + lr * 4;
#pragma unroll
      for (int r = 0; r < 4; ++r) {
        float v = acc[mi][ni][r] + bv;
        if (F32OUT) of32[(size_t)(row0 + r) * Nn + col] = v;
        else        obf[(size_t)(row0 + r) * Nn + col] = f2b(v);
      }
    }
  }
}

// ---------- kernel 4: v-section of qkvp -> vT[B,H,D,N] ----------
__global__ __launch_bounds__(256) void k_reshape_v(const u16* __restrict__ qkvp,
                                                   u16* __restrict__ vt) {
  __shared__ __align__(16) u16 vtile[96][136];   // [d][n], swizzled cols
  int blk = blockIdx.x;            // bh*8 + nt
  int bh = blk >> 3, nt = blk & 7;
  int b = bh >> 3, h = bh & 7;
  int n0 = nt * 128;
  int tid = threadIdx.x;
#pragma unroll
  for (int i = 0; i < 6; ++i) {
    int task = tid + i * 256;          // 128 rows x 12 chunks
    int r = task / 12, g = task % 12;
    short8 vv = *(const short8*)(qkvp + (size_t)(b * 1024 + n0 + r) * 2304 +
                                 1536 + h * 96 + g * 8);
    int swz = (g & 7) << 4;
#pragma unroll
    for (int j = 0; j < 8; ++j)
      vtile[g * 8 + j][r ^ swz] = (u16)vv[j];
  }
  __syncthreads();
#pragma unroll
  for (int i = 0; i < 6; ++i) {
    int task = tid + i * 256;          // 96 d x 16 chunks
    int d = task >> 4, c = task & 15;
    int swz = ((d >> 3) & 7) << 4;
    short8 v = *(const short8*)&vtile[d][(c * 8) ^ swz];
    *(short8*)(vt + ((size_t)(bh * 96) + d) * 1024 + n0 + c * 8) = v;
  }
}

// ---------- kernel 5: flash attention ----------
// block = (b,h,qt): 128 q rows, 4 waves x 32 rows; blk%8 = b -> XCD L2 locality.
// LDS: region0 = K[128][104] (26.6KB) UNION P[4][32][136] (34.8KB); Vl[96][136].
// K,V register-prefetched one tile ahead; raw barriers keep vmcnt in flight.
__global__ __launch_bounds__(256, 2) void k_attn(const u16* __restrict__ qkvp,
                                                 const u16* __restrict__ vt,
                                                 u16* __restrict__ ctx) {
  __shared__ __align__(16) u16 reg0[17408];   // 34816 B
  __shared__ __align__(16) u16 Vl[96 * 136];  // 26112 B
  int blk = blockIdx.x;
  int b = blk & 7, h = (blk >> 3) & 7, qt = blk >> 6;
  int tid = threadIdx.x, w = tid >> 6, l = tid & 63;
  int lr = l >> 4, lc = l & 15;
  int q0 = qt * 128 + w * 32;
  const u16* qptr = qkvp + (size_t)b * 1024 * 2304 + h * 96;
  const u16* kptr = qptr + 768;
  const u16* vtp  = vt + (size_t)(b * 8 + h) * 96 * 1024;
  u16* Pw = reg0 + w * (32 * 136);

  short8 qf[2][3];
#pragma unroll
  for (int mf = 0; mf < 2; ++mf)
#pragma unroll
    for (int kf = 0; kf < 3; ++kf)
      qf[mf][kf] = *(const short8*)(qptr + (size_t)(q0 + mf * 16 + lc) * 2304 +
                                    kf * 32 + lr * 8);

  float mrow[2][4], lrow[2][4];
#pragma unroll
  for (int mf = 0; mf < 2; ++mf)
#pragma unroll
    for (int r = 0; r < 4; ++r) { mrow[mf][r] = -INFINITY; lrow[mf][r] = 0.f; }
  f32x4 oacc[2][6] = {};

  short8 kpre[6], vpre[6];
#pragma unroll
  for (int i = 0; i < 6; ++i) {                 // prologue prefetch kt=0
    int idx = tid + i * 256;
    int r = idx / 12, c = idx % 12;
    kpre[i] = *(const short8*)(kptr + (size_t)r * 2304 + c * 8);
    int d = idx >> 4, cc = idx & 15;
    vpre[i] = *(const short8*)(vtp + (size_t)d * 1024 + cc * 8);
  }

  for (int kt = 0; kt < 8; ++kt) {
    BAR();   // prev PV LDS reads done everywhere
    // stage K -> reg0, V -> Vl from prefetch regs
#pragma unroll
    for (int i = 0; i < 6; ++i) {
      int idx = tid + i * 256;
      int r = idx / 12, c = idx % 12;
      *(short8*)&reg0[r * 104 + c * 8] = kpre[i];
      int d = idx >> 4, cc = idx & 15;
      *(short8*)&Vl[d * 136 + cc * 8] = vpre[i];
    }
    // prefetch K for kt+1 (latency hidden under QK^T + softmax)
    if (kt < 7) {
#pragma unroll
      for (int i = 0; i < 6; ++i) {
        int idx = tid + i * 256, r = idx / 12, c = idx % 12;
        kpre[i] = *(const short8*)(kptr + (size_t)((kt + 1) * 128 + r) * 2304 + c * 8);
      }
    }
    BAR();   // staging visible (vmcnt of kpre loads stays outstanding)

    // S = Q K^T (q pre-scaled via W/bias folding)
    f32x4 sacc[2][8] = {};
#pragma unroll
    for (int nf = 0; nf < 8; ++nf) {
#pragma unroll
      for (int kf = 0; kf < 3; ++kf) {
        short8 kb = *(const short8*)&reg0[(nf * 16 + lc) * 104 + kf * 32 + lr * 8];
        sacc[0][nf] = mfma16(qf[0][kf], kb, sacc[0][nf]);
        sacc[1][nf] = mfma16(qf[1][kf], kb, sacc[1][nf]);
      }
    }
    sacc[1][7] = fence_nops(sacc[1][7]);
#pragma unroll
    for (int mf = 0; mf < 2; ++mf)
#pragma unroll
      for (int nf = 0; nf < 8; ++nf)
        if (!(mf == 1 && nf == 7)) sacc[mf][nf] = fence0(sacc[mf][nf]);

    // online softmax; rows: 4*lr + r (+16*mf); cols: nf*16 + lc
#pragma unroll
    for (int mf = 0; mf < 2; ++mf) {
#pragma unroll
      for (int r = 0; r < 4; ++r) {
        float mx = sacc[mf][0][r];
#pragma unroll
        for (int nf = 1; nf < 8; ++nf) mx = fmaxf(mx, sacc[mf][nf][r]);
#pragma unroll
        for (int d = 1; d < 16; d <<= 1) mx = fmaxf(mx, __shfl_xor(mx, d));
        float nm = fmaxf(mrow[mf][r], mx);
        float sc = __expf(mrow[mf][r] - nm);   // 0 on first tile
        mrow[mf][r] = nm;
        float rs = 0.f;
#pragma unroll
        for (int nf = 0; nf < 8; ++nf) {
          float p = __expf(sacc[mf][nf][r] - nm);
          sacc[mf][nf][r] = p;
          rs += p;
        }
#pragma unroll
        for (int d = 1; d < 16; d <<= 1) rs += __shfl_xor(rs, d);
        lrow[mf][r] = lrow[mf][r] * sc + rs;
#pragma unroll
        for (int nf = 0; nf < 6; ++nf) oacc[mf][nf][r] *= sc;
      }
    }

    BAR();   // all waves' QK^T K-reads done before P overwrites region0

    // P -> LDS (wave-private slice of region0)
#pragma unroll
    for (int mf = 0; mf < 2; ++mf)
#pragma unroll
      for (int nf = 0; nf < 8; ++nf)
#pragma unroll
        for (int r = 0; r < 4; ++r)
          Pw[(mf * 16 + lr * 4 + r) * 136 + nf * 16 + lc] = f2b(sacc[mf][nf][r]);

    // prefetch V for kt+1 (latency hidden under PV)
    if (kt < 7) {
#pragma unroll
      for (int i = 0; i < 6; ++i) {
        int idx = tid + i * 256, d = idx >> 4, cc = idx & 15;
        vpre[i] = *(const short8*)(vtp + (size_t)d * 1024 + (kt + 1) * 128 + cc * 8);
      }
    }

    // O += P V
#pragma unroll
    for (int kf = 0; kf < 4; ++kf) {
      short8 pa0 = *(const short8*)&Pw[lc * 136 + kf * 32 + lr * 8];
      short8 pa1 = *(const short8*)&Pw[(16 + lc) * 136 + kf * 32 + lr * 8];
#pragma unroll
      for (int nf = 0; nf < 6; ++nf) {
        short8 vb = *(const short8*)&Vl[(nf * 16 + lc) * 136 + kf * 32 + lr * 8];
        oacc[0][nf] = mfma16(pa0, vb, oacc[0][nf]);
        oacc[1][nf] = mfma16(pa1, vb, oacc[1][nf]);
      }
    }
    oacc[1][5] = fence_nops(oacc[1][5]);
#pragma unroll
    for (int mf = 0; mf < 2; ++mf)
#pragma unroll
      for (int nf = 0; nf < 6; ++nf)
        if (!(mf == 1 && nf == 5)) oacc[mf][nf] = fence0(oacc[mf][nf]);
  }

#pragma unroll
  for (int mf = 0; mf < 2; ++mf) {
    float inv[4];
#pragma unroll
    for (int r = 0; r < 4; ++r) inv[r] = 1.0f / lrow[mf][r];
#pragma unroll
    for (int nf = 0; nf < 6; ++nf) {
#pragma unroll
      for (int r = 0; r < 4; ++r) {
        int row = b * 1024 + qt * 128 + w * 32 + mf * 16 + lr * 4 + r;
        ctx[(size_t)row * 768 + h * 96 + nf * 16 + lc] = f2b(oacc[mf][nf][r] * inv[r]);
      }
    }
  }
}

// ---------- launch ----------
extern "C" void kernel_launch(void* const* d_in, const int* in_sizes, int n_in,
                              void* d_out, int out_size, void* d_ws, size_t ws_size,
                              hipStream_t stream) {
  const float* x     = (const float*)d_in[0];
  const float* Wqkv  = (const float*)d_in[1];
  const float* bqkv  = (const float*)d_in[2];
  const float* Wproj = (const float*)d_in[3];
  const float* bproj = (const float*)d_in[4];
  float* out = (float*)d_out;

  char* ws = (char*)d_ws;
  u16*   xb     = (u16*)(ws);                    // 12,582,912 B (reused as ctx)
  u16*   wqkvT  = (u16*)(ws + 12582912);         //  3,538,944 B
  u16*   wprojT = (u16*)(ws + 16121856);         //  1,179,648 B
  float* bqkvp  = (float*)(ws + 17301504);       //      9,216 B
  u16*   qkvp   = (u16*)(ws + 17310720);         // 37,748,736 B
  u16*   vtb    = (u16*)(ws + 55059456);         // 12,582,912 B  (total ~67.6 MB)
  u16*   ctx    = xb;                            // xb dead after QKV GEMM

  k_cvt_x<<<6144, 256, 0, stream>>>(x, xb);
  k_tcvt<1><<<dim3(K3 / 32, Emb / 32), 256, 0, stream>>>(Wqkv, wqkvT, Emb, K3);
  k_tcvt<0><<<dim3(Emb / 32, Emb / 32), 256, 0, stream>>>(Wproj, wprojT, Emb, Emb);
  k_permbias<<<9, 256, 0, stream>>>(bqkv, bqkvp);
  k_gemm_bt<0><<<dim3(Mrows / 128, K3 / 128), 256, 0, stream>>>(
      xb, wqkvT, bqkvp, qkvp, nullptr, K3, Emb);
  k_reshape_v<<<512, 256, 0, stream>>>(qkvp, vtb);
  k_attn<<<512, 256, 0, stream>>>(qkvp, vtb, ctx);
  k_gemm_bt<1><<<dim3(Mrows / 128, Emb / 128), 256, 0, stream>>>(
      ctx, wprojT, bproj, nullptr, out, Emb, Emb);
}

// Round 3
// 156.897 us; speedup vs baseline: 1.2084x; 1.0145x over previous
//
#include <hip/hip_runtime.h>

typedef unsigned short u16;
typedef __attribute__((ext_vector_type(8))) short short8;
typedef __attribute__((ext_vector_type(4))) short short4v;
typedef __attribute__((ext_vector_type(4))) float f32x4;

#define DEV static __device__ __forceinline__

static_assert(sizeof(short8) == 16, "short8 must be 16B");

// ---------- helpers ----------
DEV u16 f2b(float f) {                       // fp32 -> bf16, round-to-nearest-even
  union { float f; unsigned u; } a; a.f = f;
  unsigned u = a.u;
  unsigned r = (u + 0x7FFFu + ((u >> 16) & 1u)) >> 16;
  return (u16)r;
}

DEV f32x4 mfma16(short8 a, short8 b, f32x4 c) {
  asm volatile("v_mfma_f32_16x16x32_bf16 %0, %1, %2, %0" : "+v"(c) : "v"(a), "v"(b));
  return c;
}
DEV f32x4 fence_nops(f32x4 c) { asm volatile("s_nop 7\n\ts_nop 7" : "+v"(c)); return c; }
DEV f32x4 fence0(f32x4 c)     { asm volatile("" : "+v"(c)); return c; }

// async global->LDS, 16B per lane; LDS dest must be wave-uniform base + lane*16
DEV void gl_lds16(const u16* g, u16* l) {
  __builtin_amdgcn_global_load_lds(
      (const __attribute__((address_space(1))) void*)g,
      (__attribute__((address_space(3))) void*)l, 16, 0, 0);
}

// ---------- problem dims ----------
constexpr int Bz = 8, Nseq = 1024, Emb = 768, Hh = 8, Dh = 96;
constexpr int Mrows = Bz * Nseq;    // 8192
constexpr int K3 = 3 * Emb;         // 2304
// 768^-0.5 * log2(e): softmax done in exp2 domain (saves a mul per S element)
constexpr float QSCALE = 0.05205982021128899f;

// ---------- kernel 1: x fp32 -> bf16 ----------
__global__ __launch_bounds__(256) void k_cvt_x(const float* __restrict__ src,
                                               u16* __restrict__ dst) {
  int i = (blockIdx.x * 256 + threadIdx.x) * 4;
  float4 v = *(const float4*)(src + i);
  short4v o;
  o[0] = (short)f2b(v.x); o[1] = (short)f2b(v.y);
  o[2] = (short)f2b(v.z); o[3] = (short)f2b(v.w);
  *(short4v*)(dst + i) = o;
}

// ---------- kernel 2: transpose + cvt (+optional qkv column permutation) ----------
template <int PERM>
__global__ __launch_bounds__(256) void k_tcvt(const float* __restrict__ src,
                                              u16* __restrict__ dst, int R, int C) {
  __shared__ float t[32][33];
  int bx = blockIdx.x * 32;   // col tile in src
  int by = blockIdx.y * 32;   // row tile in src
  int c = threadIdx.x & 31, r8 = threadIdx.x >> 5;
#pragma unroll
  for (int p = 0; p < 4; ++p) {
    int r = r8 + p * 8;
    t[r][c] = src[(size_t)(by + r) * C + bx + c];
  }
  __syncthreads();
#pragma unroll
  for (int p = 0; p < 4; ++p) {
    int r = r8 + p * 8;
    int co = bx + r;           // dst row before permutation = src col
    int row = co;
    float mul = 1.f;
    if (PERM) {
      int h = co / 288, rem = co - h * 288;
      int d = rem / 3, s = rem - d * 3;
      row = s * 768 + h * 96 + d;
      if (s == 0) mul = QSCALE;
    }
    dst[(size_t)row * R + by + c] = f2b(t[c][r] * mul);
  }
}

// ---------- kernel 2b: permuted (and q-scaled) qkv bias, fp32 ----------
__global__ __launch_bounds__(256) void k_permbias(const float* __restrict__ b,
                                                  float* __restrict__ bp) {
  int co = blockIdx.x * 256 + threadIdx.x;
  if (co < 2304) {
    int h = co / 288, rem = co - h * 288, d = rem / 3, s = rem - d * 3;
    bp[s * 768 + h * 96 + d] = b[co] * (s == 0 ? QSCALE : 1.f);
  }
}

// ---------- kernel 3: GEMM  C[M][Nn] = A[M][K] * Bt[Nn][K]^T + bias ----------
// MODE 0: QKV gemm. cols<1536 -> LDS-transposed bf16 store to obf[.][2304];
//         cols>=1536 -> direct store into vT[B*H*96][1024] (kills reshape kernel).
// MODE 1: proj gemm, f32 direct store.
template <int MODE>
__global__ __launch_bounds__(256, 2) void k_gemm_bt(
    const u16* __restrict__ A, const u16* __restrict__ Bt,
    const float* __restrict__ bias,
    u16* __restrict__ obf, u16* __restrict__ vtb, float* __restrict__ of32,
    int Nn, int Kdim) {
  __shared__ __align__(16) u16 Al[128 * 32];
  __shared__ __align__(16) u16 Bl[128 * 32];
  __shared__ __align__(16) u16 Cst[4][32 * 88];   // epilogue transpose (MODE 0)
  int m0 = blockIdx.x * 128, n0 = blockIdx.y * 128;
  int tid = threadIdx.x;
  int w = tid >> 6, l = tid & 63, lr = l >> 4, lc = l & 15;
  int wr = w >> 1, wc = w & 1;
  f32x4 acc[4][4] = {};
  int nkt = Kdim >> 5;
  for (int kt = 0; kt < nkt; ++kt) {
    __syncthreads();
#pragma unroll
    for (int i = 0; i < 2; ++i) {
      int idx = i * 256 + tid;              // 512 chunks of 16B per matrix
      int r = idx >> 2, c8 = (idx & 3) * 8;
      gl_lds16(A + (size_t)(m0 + r) * Kdim + kt * 32 + c8, &Al[idx * 8]);
      gl_lds16(Bt + (size_t)(n0 + r) * Kdim + kt * 32 + c8, &Bl[idx * 8]);
    }
    __syncthreads();
    short8 af[4];
#pragma unroll
    for (int mi = 0; mi < 4; ++mi)
      af[mi] = *(const short8*)&Al[(wr * 64 + mi * 16 + lc) * 32 + lr * 8];
#pragma unroll
    for (int ni = 0; ni < 4; ++ni) {
      short8 bf = *(const short8*)&Bl[(wc * 64 + ni * 16 + lc) * 32 + lr * 8];
#pragma unroll
      for (int mi = 0; mi < 4; ++mi)
        acc[mi][ni] = mfma16(af[mi], bf, acc[mi][ni]);
    }
  }
  acc[3][3] = fence_nops(acc[3][3]);
#pragma unroll
  for (int mi = 0; mi < 4; ++mi)
#pragma unroll
    for (int ni = 0; ni < 4; ++ni)
      if (!(mi == 3 && ni == 3)) acc[mi][ni] = fence0(acc[mi][ni]);

  if (MODE == 0) {
    if (n0 < 1536) {
      // transposed store through per-wave LDS (coalesced 16B global stores)
      u16* Cb = &Cst[w][0];
#pragma unroll
      for (int mi2 = 0; mi2 < 2; ++mi2) {
#pragma unroll
        for (int mh = 0; mh < 2; ++mh) {
          int mi = mi2 * 2 + mh;
#pragma unroll
          for (int ni = 0; ni < 4; ++ni) {
            float bv = bias[n0 + wc * 64 + ni * 16 + lc];
#pragma unroll
            for (int r = 0; r < 4; ++r)
              Cb[(mh * 16 + lr * 4 + r) * 88 + ni * 16 + lc] =
                  f2b(acc[mi][ni][r] + bv);
          }
        }
#pragma unroll
        for (int i = 0; i < 4; ++i) {
          int idx = i * 64 + l;
          int row = idx >> 3, c8 = idx & 7;
          short8 vv = *(const short8*)&Cb[row * 88 + c8 * 8];
          int grow = m0 + wr * 64 + mi2 * 32 + row;
          int gcol = n0 + wc * 64 + c8 * 8;
          *(short8*)(obf + (size_t)grow * Nn + gcol) = vv;
        }
      }
    } else {
      // V section: write directly in vT layout [(b*8+h)*96+d][1024]
#pragma unroll
      for (int mi = 0; mi < 4; ++mi) {
#pragma unroll
        for (int ni = 0; ni < 4; ++ni) {
          int col = n0 + wc * 64 + ni * 16 + lc;
          float bv = bias[col];
          int dall = col - 1536;                       // = h*96 + d
          int row0 = m0 + wr * 64 + mi * 16 + lr * 4;  // rows 4-aligned, same b
          short4v o4;
#pragma unroll
          for (int r = 0; r < 4; ++r) o4[r] = (short)f2b(acc[mi][ni][r] + bv);
          *(short4v*)(vtb + ((size_t)(row0 >> 10) * 768 + dall) * 1024 +
                      (row0 & 1023)) = o4;
        }
      }
    }
  } else {
#pragma unroll
    for (int mi = 0; mi < 4; ++mi) {
#pragma unroll
      for (int ni = 0; ni < 4; ++ni) {
        int col = n0 + wc * 64 + ni * 16 + lc;
        float bv = bias[col];
        int row0 = m0 + wr * 64 + mi * 16 + lr * 4;
#pragma unroll
        for (int r = 0; r < 4; ++r)
          of32[(size_t)(row0 + r) * Nn + col] = acc[mi][ni][r] + bv;
      }
    }
  }
}

// ---------- kernel 4: flash attention ----------
// block = (qt,h,b) with b fastest (XCD L2 locality). 4 waves x 32 q rows.
// K: double-buffered LDS via global_load_lds, ONE barrier per kv-tile.
// V: read from L2 with 2-deep register prefetch. P: per-wave 32x32 LDS chunk.
// softmax: exp2-domain (scale folded into Wq), defer-max (THR=8).
__global__ __launch_bounds__(256, 2) void k_attn(const u16* __restrict__ qkvp,
                                                 const u16* __restrict__ vt,
                                                 u16* __restrict__ ctx) {
  __shared__ __align__(16) u16 Kb[2][128 * 96];   // 49152 B (reused for ctx store)
  __shared__ __align__(16) u16 Pl[4][32 * 40];    // 10240 B
  int blk = blockIdx.x;
  int b = blk & 7, h = (blk >> 3) & 7, qt = blk >> 6;
  int tid = threadIdx.x, w = tid >> 6, l = tid & 63;
  int lr = l >> 4, lc = l & 15;
  int q0 = qt * 128 + w * 32;
  const u16* qptr = qkvp + (size_t)b * 1024 * 2304 + h * 96;
  const u16* kptr = qptr + 768;
  const u16* vtp  = vt + (size_t)(b * 768 + h * 96) * 1024;
  u16* Pw = Pl[w];

  // staging offsets (same every tile)
  int soff[6], doff[6];
#pragma unroll
  for (int i = 0; i < 6; ++i) {
    int idx = i * 256 + tid;
    soff[i] = (idx / 12) * 2304 + (idx % 12) * 8;
    doff[i] = idx * 8;
  }

  short8 qf[2][3];
#pragma unroll
  for (int mf = 0; mf < 2; ++mf)
#pragma unroll
    for (int kf = 0; kf < 3; ++kf)
      qf[mf][kf] = *(const short8*)(qptr + (size_t)(q0 + mf * 16 + lc) * 2304 +
                                    kf * 32 + lr * 8);

  float mrow[2][4], lrow[2][4];
#pragma unroll
  for (int mf = 0; mf < 2; ++mf)
#pragma unroll
    for (int r = 0; r < 4; ++r) { mrow[mf][r] = -INFINITY; lrow[mf][r] = 0.f; }
  f32x4 oacc[2][6] = {};

  // prologue: stage K tile 0
#pragma unroll
  for (int i = 0; i < 6; ++i) gl_lds16(kptr + soff[i], &Kb[0][0] + doff[i]);
  __syncthreads();

  for (int kt = 0; kt < 8; ++kt) {
    const u16* Kc = Kb[kt & 1];
    if (kt < 7) {                         // async-stage next tile into other buffer
      const u16* kb = kptr + (size_t)(kt + 1) * 128 * 2304;
      u16* db = Kb[(kt + 1) & 1];
#pragma unroll
      for (int i = 0; i < 6; ++i) gl_lds16(kb + soff[i], db + doff[i]);
    }

    // S = Q K^T (scale+log2e folded into q)
    f32x4 sacc[2][8] = {};
    __builtin_amdgcn_s_setprio(1);
#pragma unroll
    for (int nf = 0; nf < 8; ++nf) {
#pragma unroll
      for (int kf = 0; kf < 3; ++kf) {
        short8 kb = *(const short8*)&Kc[(nf * 16 + lc) * 96 + kf * 32 + lr * 8];
        sacc[0][nf] = mfma16(qf[0][kf], kb, sacc[0][nf]);
        sacc[1][nf] = mfma16(qf[1][kf], kb, sacc[1][nf]);
      }
    }
    __builtin_amdgcn_s_setprio(0);

    // V prefetch for kf=0 (latency hides under softmax)
    short8 vb[2][6];
    const u16* vkt = vtp + kt * 128;
#pragma unroll
    for (int nf = 0; nf < 6; ++nf)
      vb[0][nf] = *(const short8*)(vkt + (size_t)(nf * 16 + lc) * 1024 + lr * 8);

    sacc[1][7] = fence_nops(sacc[1][7]);
#pragma unroll
    for (int mf = 0; mf < 2; ++mf)
#pragma unroll
      for (int nf = 0; nf < 8; ++nf)
        if (!(mf == 1 && nf == 7)) sacc[mf][nf] = fence0(sacc[mf][nf]);

    // online softmax in exp2 domain, deferred max (P bounded by 2^8)
#pragma unroll
    for (int mf = 0; mf < 2; ++mf) {
#pragma unroll
      for (int r = 0; r < 4; ++r) {
        float mx = sacc[mf][0][r];
#pragma unroll
        for (int nf = 1; nf < 8; ++nf) mx = fmaxf(mx, sacc[mf][nf][r]);
#pragma unroll
        for (int d = 1; d < 16; d <<= 1) mx = fmaxf(mx, __shfl_xor(mx, d));
        if (mx > mrow[mf][r] + 8.f) {     // rare after first tile
          float sc = exp2f(mrow[mf][r] - mx);   // 0 on first tile
          mrow[mf][r] = mx;
          lrow[mf][r] *= sc;
#pragma unroll
          for (int nf = 0; nf < 6; ++nf) oacc[mf][nf][r] *= sc;
        }
        float m = mrow[mf][r], rs = 0.f;
#pragma unroll
        for (int nf = 0; nf < 8; ++nf) {
          float p = exp2f(sacc[mf][nf][r] - m);
          sacc[mf][nf][r] = p;
          rs += p;
        }
#pragma unroll
        for (int d = 1; d < 16; d <<= 1) rs += __shfl_xor(rs, d);
        lrow[mf][r] += rs;
      }
    }

    // O += P V, P chunked 32-k at a time through per-wave LDS
#pragma unroll
    for (int kf = 0; kf < 4; ++kf) {
      int cb = kf & 1;
#pragma unroll
      for (int mf = 0; mf < 2; ++mf)
#pragma unroll
        for (int nn = 0; nn < 2; ++nn)
#pragma unroll
          for (int r = 0; r < 4; ++r)
            Pw[(mf * 16 + lr * 4 + r) * 40 + nn * 16 + lc] =
                f2b(sacc[mf][2 * kf + nn][r]);
      if (kf < 3) {                        // V prefetch for kf+1
#pragma unroll
        for (int nf = 0; nf < 6; ++nf)
          vb[cb ^ 1][nf] = *(const short8*)(vkt + (size_t)(nf * 16 + lc) * 1024 +
                                            (kf + 1) * 32 + lr * 8);
      }
      short8 pa0 = *(const short8*)&Pw[lc * 40 + lr * 8];
      short8 pa1 = *(const short8*)&Pw[(16 + lc) * 40 + lr * 8];
      __builtin_amdgcn_s_setprio(1);
#pragma unroll
      for (int nf = 0; nf < 6; ++nf) {
        oacc[0][nf] = mfma16(pa0, vb[cb][nf], oacc[0][nf]);
        oacc[1][nf] = mfma16(pa1, vb[cb][nf], oacc[1][nf]);
      }
      __builtin_amdgcn_s_setprio(0);
    }
    oacc[1][5] = fence_nops(oacc[1][5]);   // MFMA->VALU hazard (rescale next kt)

    __syncthreads();   // next K tile staged; all waves done with Kc
  }

#pragma unroll
  for (int mf = 0; mf < 2; ++mf)
#pragma unroll
    for (int nf = 0; nf < 6; ++nf) oacc[mf][nf] = fence0(oacc[mf][nf]);

  // ctx store via LDS transpose (reuse Kb): coalesced 16B stores
  u16* Cw = &Kb[0][0] + w * (32 * 104);
  float inv[2][4];
#pragma unroll
  for (int mf = 0; mf < 2; ++mf)
#pragma unroll
    for (int r = 0; r < 4; ++r) inv[mf][r] = 1.0f / lrow[mf][r];
#pragma unroll
  for (int mf = 0; mf < 2; ++mf)
#pragma unroll
    for (int nf = 0; nf < 6; ++nf)
#pragma unroll
      for (int r = 0; r < 4; ++r)
        Cw[(mf * 16 + lr * 4 + r) * 104 + nf * 16 + lc] =
            f2b(oacc[mf][nf][r] * inv[mf][r]);
  int crow0 = b * 1024 + qt * 128 + w * 32;
#pragma unroll
  for (int i = 0; i < 6; ++i) {
    int idx = i * 64 + l;                // 384 chunks: 32 rows x 12
    int row = idx / 12, c16 = idx % 12;
    short8 vv = *(const short8*)&Cw[row * 104 + c16 * 8];
    *(short8*)(ctx + (size_t)(crow0 + row) * 768 + h * 96 + c16 * 8) = vv;
  }
}

// ---------- launch ----------
extern "C" void kernel_launch(void* const* d_in, const int* in_sizes, int n_in,
                              void* d_out, int out_size, void* d_ws, size_t ws_size,
                              hipStream_t stream) {
  const float* x     = (const float*)d_in[0];
  const float* Wqkv  = (const float*)d_in[1];
  const float* bqkv  = (const float*)d_in[2];
  const float* Wproj = (const float*)d_in[3];
  const float* bproj = (const float*)d_in[4];
  float* out = (float*)d_out;

  char* ws = (char*)d_ws;
  u16*   xb     = (u16*)(ws);                    // 12,582,912 B (reused as ctx)
  u16*   wqkvT  = (u16*)(ws + 12582912);         //  3,538,944 B
  u16*   wprojT = (u16*)(ws + 16121856);         //  1,179,648 B
  float* bqkvp  = (float*)(ws + 17301504);       //      9,216 B
  u16*   qkvp   = (u16*)(ws + 17310720);         // 37,748,736 B (q,k cols only)
  u16*   vtb    = (u16*)(ws + 55059456);         // 12,582,912 B
  u16*   ctx    = xb;                            // xb dead after QKV GEMM

  k_cvt_x<<<6144, 256, 0, stream>>>(x, xb);
  k_tcvt<1><<<dim3(K3 / 32, Emb / 32), 256, 0, stream>>>(Wqkv, wqkvT, Emb, K3);
  k_tcvt<0><<<dim3(Emb / 32, Emb / 32), 256, 0, stream>>>(Wproj, wprojT, Emb, Emb);
  k_permbias<<<9, 256, 0, stream>>>(bqkv, bqkvp);
  k_gemm_bt<0><<<dim3(Mrows / 128, K3 / 128), 256, 0, stream>>>(
      xb, wqkvT, bqkvp, qkvp, vtb, nullptr, K3, Emb);
  k_attn<<<512, 256, 0, stream>>>(qkvp, vtb, ctx);
  k_gemm_bt<1><<<dim3(Mrows / 128, Emb / 128), 256, 0, stream>>>(
      ctx, wprojT, bproj, nullptr, nullptr, out, Emb, Emb);
}